// Round 12
// baseline (519.149 us; speedup 1.0000x reference)
//
#include <hip/hip_runtime.h>
#include <hip/hip_bf16.h>

#define MN 16384
#define SPLITS 4
#define KSLICE (MN / SPLITS)     // 4096
#define BK 256
#define NSTEPS (KSLICE / BK)     // 16

typedef float f32x4 __attribute__((ext_vector_type(4)));
typedef int   i32x4 __attribute__((ext_vector_type(4)));

#define A8S 32768.0f             // adj * 2^15 in [0,2)
#define SB1 64.0f                // support1 * 2^6
#define SB2 4096.0f              // support2 * 2^12
#define SC1 (1.0f / (32768.0f * 64.0f))     // 2^-21
#define SC2 (1.0f / (32768.0f * 4096.0f))   // 2^-27

__device__ __forceinline__ void async16(void* lds, const void* g) {
  __builtin_amdgcn_global_load_lds(
      (const __attribute__((address_space(1))) unsigned int*)g,
      (__attribute__((address_space(3))) unsigned int*)lds, 16, 0, 0);
}

// fp8-fragment order for a [K x 128] operand: byte[(U*128 + col)*8 + j]
// holds fp8(val[k = U*8 + j][col]).  (unit U = k>>3, j = k&7)

// ---------------------------------------------------------------------------
// K1: support1 = x @ W2 -> fp8 e4m3 (x SB1) in fragment order.
// ---------------------------------------------------------------------------
__global__ __launch_bounds__(256)
void k1_xw2(const float* __restrict__ x, const float* __restrict__ W2,
            unsigned char* __restrict__ B1) {
  __shared__ __align__(16) float xs[64 * 128];
  const int t = threadIdx.x;
  const long rowbase = (long)blockIdx.x * 64;
  const f32x4* xg = (const f32x4*)(x + rowbase * 128);
  f32x4* xl = (f32x4*)xs;
#pragma unroll
  for (int i = 0; i < 8; ++i) xl[t + 256 * i] = xg[t + 256 * i];
  __syncthreads();
  const int r0 = (t >> 5) * 8;   // 8 rows per thread (8-aligned)
  const int c0 = (t & 31) * 4;   // 4 cols per thread
  float acc[8][4] = {};
  for (int k = 0; k < 128; k += 4) {
    f32x4 w[4];
#pragma unroll
    for (int kk = 0; kk < 4; ++kk) w[kk] = *(const f32x4*)(W2 + (k + kk) * 128 + c0);
#pragma unroll
    for (int i = 0; i < 8; ++i) {
      f32x4 xv = *(const f32x4*)(xs + (r0 + i) * 128 + k);
#pragma unroll
      for (int kk = 0; kk < 4; ++kk)
#pragma unroll
        for (int j = 0; j < 4; ++j) acc[i][j] += xv[kk] * w[kk][j];
    }
  }
  const long U = (rowbase + r0) >> 3;
  i32x4 wv0, wv1;
#pragma unroll
  for (int j = 0; j < 4; ++j) {
    int lo = __builtin_amdgcn_cvt_pk_fp8_f32(acc[0][j] * SB1, acc[1][j] * SB1, 0, false);
    lo     = __builtin_amdgcn_cvt_pk_fp8_f32(acc[2][j] * SB1, acc[3][j] * SB1, lo, true);
    int hi = __builtin_amdgcn_cvt_pk_fp8_f32(acc[4][j] * SB1, acc[5][j] * SB1, 0, false);
    hi     = __builtin_amdgcn_cvt_pk_fp8_f32(acc[6][j] * SB1, acc[7][j] * SB1, hi, true);
    if (j < 2) { wv0[2 * j] = lo; wv0[2 * j + 1] = hi; }
    else       { wv1[2 * (j - 2)] = lo; wv1[2 * (j - 2) + 1] = hi; }
  }
  *(i32x4*)(B1 + (U * 128 + c0) * 8)      = wv0;
  *(i32x4*)(B1 + (U * 128 + c0) * 8 + 16) = wv1;
}

// ---------------------------------------------------------------------------
// Big kernel v11: BK=256 — 1 KB per adj-row visit per step.
// 256 threads / 4 waves; 64-row tile; 16 K-steps; grid 1024 = 2 blocks/CU
// (LDS 64 KB/block), 8 waves/CU, VGPR budget 256 (no spill risk).
// K-relabel: lane(g,cl) owns k = 256t + 64g + [0,64): 16 back-to-back
// dwordx4 = 256B contiguous per lane; 4 g-groups = 1 KB contiguous per row.
// CRITICAL issue order per step (R7's bug, fixed): A(t) loads FIRST (oldest)
// -> stage B(t+1) -> convert (compiler's A-wait leaves stage in flight,
// in-order vmcnt) -> 64 MFMA -> counted vmcnt -> raw barrier. Stage is
// issued ~20k cycles before use, never drained early.
// B fragment mapping: global unit U = 32t + 8g + j  <->  A k = 256t+64g+8j.
// AMODE 0: A f32 -> cvt fp8 once; bytes feed MFMA + A8 copy (64 B/lane,
//          contiguous, NT stores).
// AMODE 1: A from A8 copy (4 dwordx4/lane/step, contiguous).
// AMODE 2: AMODE 0 without the side-copy (ws fallback).
// ---------------------------------------------------------------------------
template <int AMODE>
__global__ __launch_bounds__(256)
void big_mm(const float* __restrict__ A, const unsigned char* __restrict__ A8r,
            unsigned char* __restrict__ A8w, const unsigned char* __restrict__ B8,
            float sc, float* __restrict__ P) {
  __shared__ __align__(16) unsigned char Bs[2][32768];
  const int tid  = threadIdx.x;
  const int wid  = tid >> 6;     // 0..3
  const int lane = tid & 63;
  const int g    = lane >> 4;    // k-group
  const int cl   = lane & 15;    // A-row / B-col / C-col within tile
  const int tile_m = blockIdx.x & 255;
  const int s      = blockIdx.x >> 8;
  const long k0 = (long)s * KSLICE;

  // B staging: 32 KB/step by 256 threads = 8 rounds x 4 KB (wave-uniform dst)
  const char* bsrc = (const char*)B8 + k0 * 128 + (long)wid * 1024 + (long)lane * 16;
  const float* aptr = nullptr;
  if constexpr (AMODE != 1)
    aptr = A + (long)(tile_m * 64 + wid * 16 + cl) * MN + k0 + g * 64;
  const long c8base = (long)blockIdx.x * (NSTEPS * 16384L) + (long)tid * 64;

  f32x4 acc[8] = {};

  // prologue: stage step 0 into bank 0
#pragma unroll
  for (int r = 0; r < 8; ++r)
    async16(&Bs[0][0] + r * 4096 + wid * 1024, bsrc + r * 4096);
  __syncthreads();

  for (int t = 0; t < NSTEPS; ++t) {
    const int bank = t & 1;
    int pk[16];
    if constexpr (AMODE == 1) {
      // (1) A8 loads FIRST (oldest)
      const unsigned char* ap = A8r + c8base + (long)t * 16384;
      i32x4 q0 = *(const i32x4*)ap;
      i32x4 q1 = *(const i32x4*)(ap + 16);
      i32x4 q2 = *(const i32x4*)(ap + 32);
      i32x4 q3 = *(const i32x4*)(ap + 48);
      // (2) stage B(t+1)
      if (t + 1 < NSTEPS) {
        const char* src = bsrc + (long)(t + 1) * 32768;
#pragma unroll
        for (int r = 0; r < 8; ++r)
          async16(&Bs[bank ^ 1][0] + r * 4096 + wid * 1024, src + r * 4096);
      }
      __builtin_amdgcn_sched_barrier(0);
#pragma unroll
      for (int d = 0; d < 4; ++d) {
        pk[d]      = q0[d];
        pk[4 + d]  = q1[d];
        pk[8 + d]  = q2[d];
        pk[12 + d] = q3[d];
      }
    } else {
      // (1) A loads FIRST (oldest): 16 back-to-back dwordx4, 256B contiguous
      const float* ap = aptr + (long)t * BK;
      f32x4 av[16];
#pragma unroll
      for (int i = 0; i < 16; ++i) av[i] = *(const f32x4*)(ap + 4 * i);
      // (2) stage B(t+1): stays in flight through convert + MFMA
      if (t + 1 < NSTEPS) {
        const char* src = bsrc + (long)(t + 1) * 32768;
#pragma unroll
        for (int r = 0; r < 8; ++r)
          async16(&Bs[bank ^ 1][0] + r * 4096 + wid * 1024, src + r * 4096);
      }
      __builtin_amdgcn_sched_barrier(0);   // pin: A older, stage before convert
      // (3) convert: compiler waits on A incrementally; stage NOT drained
#pragma unroll
      for (int i = 0; i < 16; ++i) {
        int w = __builtin_amdgcn_cvt_pk_fp8_f32(av[i][0] * A8S, av[i][1] * A8S, 0, false);
        pk[i] = __builtin_amdgcn_cvt_pk_fp8_f32(av[i][2] * A8S, av[i][3] * A8S, w, true);
      }
      if constexpr (AMODE == 0) {
        unsigned char* wp = A8w + c8base + (long)t * 16384;
#pragma unroll
        for (int i = 0; i < 4; ++i) {
          i32x4 st = {pk[4 * i], pk[4 * i + 1], pk[4 * i + 2], pk[4 * i + 3]};
          __builtin_nontemporal_store(st, (i32x4*)(wp + 16 * i));
        }
      }
    }

    // (4) MFMA: 8 k-units x 8 col-tiles; unit (g,j) at LDS (8g+j)*1024
    const char* bb = (const char*)&Bs[bank][0] + g * 8192 + cl * 8;
#pragma unroll
    for (int j = 0; j < 8; ++j) {
      const long a = ((long)(unsigned)pk[2 * j + 1] << 32) | (unsigned)pk[2 * j];
#pragma unroll
      for (int c = 0; c < 8; ++c) {
        long b = *(const long*)(bb + j * 1024 + c * 128);
        acc[c] = __builtin_amdgcn_mfma_f32_16x16x32_fp8_fp8(a, b, acc[c], 0, 0, 0);
      }
    }

    // (5) retire stage(t+1) exactly (stores stay in flight); raw barrier
    if (t + 1 < NSTEPS) {
      if constexpr (AMODE == 0) asm volatile("s_waitcnt vmcnt(4)" ::: "memory");
      else                      asm volatile("s_waitcnt vmcnt(0)" ::: "memory");
      __builtin_amdgcn_s_barrier();
    }
  }

  // C/D layout (HW-verified, dtype-independent): col=lane&15, row=4*(lane>>4)+q
  float* pb = P + ((long)s * MN + tile_m * 64 + wid * 16) * 128;
#pragma unroll
  for (int c = 0; c < 8; ++c)
#pragma unroll
    for (int q = 0; q < 4; ++q)
      __builtin_nontemporal_store(acc[c][q] * sc,
                                  &pb[(g * 4 + q) * 128 + 16 * c + cl]);
}

// ---------------------------------------------------------------------------
// K3: LH = sum_s P[s] + b2 (tile in LDS); then
//     B2 = fp8frag(LH @ W4 * SB2);  R = LH @ res_w^T + res_b + b4
// ---------------------------------------------------------------------------
__global__ __launch_bounds__(256)
void k3_mid(const float* __restrict__ P, const float* __restrict__ b2,
            const float* __restrict__ W4, const float* __restrict__ res_w,
            const float* __restrict__ b4, const float* __restrict__ res_b,
            unsigned char* __restrict__ B2, float* __restrict__ Rr) {
  __shared__ __align__(16) float hs[64 * 128];
  const int t = threadIdx.x;
  const long rowbase = (long)blockIdx.x * 64;
  const long base = rowbase * 32;            // f32x4 units (128/4 per row)
  const f32x4* P0 = (const f32x4*)P + base;
  const f32x4* P1 = (const f32x4*)P + (long)MN * 32 + base;
  const f32x4* P2 = (const f32x4*)P + 2L * MN * 32 + base;
  const f32x4* P3 = (const f32x4*)P + 3L * MN * 32 + base;
  const f32x4* b2v = (const f32x4*)b2;
  f32x4* hl = (f32x4*)hs;
#pragma unroll
  for (int i = 0; i < 8; ++i) {
    int idx = t + 256 * i;
    f32x4 v = __builtin_nontemporal_load(P0 + idx);
    v += __builtin_nontemporal_load(P1 + idx);
    v += __builtin_nontemporal_load(P2 + idx);
    v += __builtin_nontemporal_load(P3 + idx);
    hl[idx] = v + b2v[idx & 31];
  }
  __syncthreads();
  const int r0 = (t >> 5) * 8;
  const int c0 = (t & 31) * 4;
  float acc2[8][4] = {};
  float accR[8][4] = {};
  for (int k = 0; k < 128; k += 4) {
    f32x4 w4v[4], rwv[4];
#pragma unroll
    for (int kk = 0; kk < 4; ++kk) w4v[kk] = *(const f32x4*)(W4 + (k + kk) * 128 + c0);
#pragma unroll
    for (int j = 0; j < 4; ++j) rwv[j] = *(const f32x4*)(res_w + (c0 + j) * 128 + k);
#pragma unroll
    for (int i = 0; i < 8; ++i) {
      f32x4 xv = *(const f32x4*)(hs + (r0 + i) * 128 + k);
#pragma unroll
      for (int kk = 0; kk < 4; ++kk)
#pragma unroll
        for (int j = 0; j < 4; ++j) {
          acc2[i][j] += xv[kk] * w4v[kk][j];
          accR[i][j] += xv[kk] * rwv[j][kk];
        }
    }
  }
  const long U = (rowbase + r0) >> 3;
  i32x4 wv0, wv1;
#pragma unroll
  for (int j = 0; j < 4; ++j) {
    int lo = __builtin_amdgcn_cvt_pk_fp8_f32(acc2[0][j] * SB2, acc2[1][j] * SB2, 0, false);
    lo     = __builtin_amdgcn_cvt_pk_fp8_f32(acc2[2][j] * SB2, acc2[3][j] * SB2, lo, true);
    int hi = __builtin_amdgcn_cvt_pk_fp8_f32(acc2[4][j] * SB2, acc2[5][j] * SB2, 0, false);
    hi     = __builtin_amdgcn_cvt_pk_fp8_f32(acc2[6][j] * SB2, acc2[7][j] * SB2, hi, true);
    if (j < 2) { wv0[2 * j] = lo; wv0[2 * j + 1] = hi; }
    else       { wv1[2 * (j - 2)] = lo; wv1[2 * (j - 2) + 1] = hi; }
  }
  *(i32x4*)(B2 + (U * 128 + c0) * 8)      = wv0;
  *(i32x4*)(B2 + (U * 128 + c0) * 8 + 16) = wv1;

  const f32x4 b4v = *(const f32x4*)(b4 + c0);
  const f32x4 rbv = *(const f32x4*)(res_b + c0);
#pragma unroll
  for (int i = 0; i < 8; ++i) {
    f32x4 rv;
#pragma unroll
    for (int j = 0; j < 4; ++j) rv[j] = accR[i][j];
    rv += b4v + rbv;
    *(f32x4*)(Rr + (rowbase + r0 + i) * 128 + c0) = rv;
  }
}

// ---------------------------------------------------------------------------
// K5: out = sum_s P[s] + R
// ---------------------------------------------------------------------------
__global__ __launch_bounds__(256)
void k5_out(const float* __restrict__ P, const float* __restrict__ Rr,
            float* __restrict__ out) {
  const long i = (long)blockIdx.x * 256 + threadIdx.x;   // f32x4 index
  const f32x4* P0 = (const f32x4*)P;
  const f32x4* P1 = P0 + (long)MN * 32;
  const f32x4* P2 = P0 + 2L * MN * 32;
  const f32x4* P3 = P0 + 3L * MN * 32;
  f32x4 v = __builtin_nontemporal_load(P0 + i);
  v += __builtin_nontemporal_load(P1 + i);
  v += __builtin_nontemporal_load(P2 + i);
  v += __builtin_nontemporal_load(P3 + i);
  v += *((const f32x4*)Rr + i);
  __builtin_nontemporal_store(v, (f32x4*)out + i);
}

extern "C" void kernel_launch(void* const* d_in, const int* in_sizes, int n_in,
                              void* d_out, int out_size, void* d_ws, size_t ws_size,
                              hipStream_t stream) {
  const float* x     = (const float*)d_in[0];
  const float* adj   = (const float*)d_in[1];
  const float* W2    = (const float*)d_in[2];
  const float* b2    = (const float*)d_in[3];
  const float* W4    = (const float*)d_in[4];
  const float* b4    = (const float*)d_in[5];
  const float* res_w = (const float*)d_in[6];
  const float* res_b = (const float*)d_in[7];
  float* out = (float*)d_out;

  char* ws = (char*)d_ws;
  unsigned char* B1 = (unsigned char*)ws;                  // 2 MB fp8-frag s1
  unsigned char* B2 = (unsigned char*)(ws + (4L << 20));   // 2 MB fp8-frag s2
  float* Rr = (float*)(ws + (8L << 20));                   // 8 MB residual
  float* P  = (float*)(ws + (16L << 20));                  // 32 MB f32 partials
  unsigned char* A8 = (unsigned char*)(ws + (48L << 20));  // 256 MB fp8 adj

  const size_t need = (48L << 20) + (size_t)MN * MN;  // 316.8 MB
  const bool fp8_copy = ws_size >= need;

  const int BIGGRID = 256 * SPLITS;   // 1024 blocks (64-row tiles)
  k1_xw2<<<dim3(256), dim3(256), 0, stream>>>(x, W2, B1);
  if (fp8_copy) {
    big_mm<0><<<dim3(BIGGRID), dim3(256), 0, stream>>>(adj, nullptr, A8, B1, SC1, P);
    k3_mid<<<dim3(256), dim3(256), 0, stream>>>(P, b2, W4, res_w, b4, res_b, B2, Rr);
    big_mm<1><<<dim3(BIGGRID), dim3(256), 0, stream>>>(nullptr, A8, nullptr, B2, SC2, P);
  } else {
    big_mm<2><<<dim3(BIGGRID), dim3(256), 0, stream>>>(adj, nullptr, nullptr, B1, SC1, P);
    k3_mid<<<dim3(256), dim3(256), 0, stream>>>(P, b2, W4, res_w, b4, res_b, B2, Rr);
    big_mm<2><<<dim3(BIGGRID), dim3(256), 0, stream>>>(adj, nullptr, nullptr, B2, SC2, P);
  }
  k5_out<<<dim3(2048), dim3(256), 0, stream>>>(P, Rr, out);
}

// Round 13
// 426.155 us; speedup vs baseline: 1.2182x; 1.2182x over previous
//
#include <hip/hip_runtime.h>
#include <hip/hip_bf16.h>

#define MN 16384
#define SPLITS 4
#define KSLICE (MN / SPLITS)     // 4096
#define BK 64
#define NSTEPS (KSLICE / BK)     // 64

typedef float f32x4 __attribute__((ext_vector_type(4)));
typedef int   i32x4 __attribute__((ext_vector_type(4)));

#define A8S 32768.0f             // adj * 2^15 in [0,2)
#define SB1 64.0f                // support1 * 2^6
#define SB2 4096.0f              // support2 * 2^12
#define SC1 (1.0f / (32768.0f * 64.0f))     // 2^-21
#define SC2 (1.0f / (32768.0f * 4096.0f))   // 2^-27

__device__ __forceinline__ void async16(void* lds, const void* g) {
  __builtin_amdgcn_global_load_lds(
      (const __attribute__((address_space(1))) unsigned int*)g,
      (__attribute__((address_space(3))) unsigned int*)lds, 16, 0, 0);
}

// fp8-fragment order for a [K x 128] operand: byte[(U*128 + col)*8 + j]
// holds fp8(val[k = U*8 + j][col]).  (unit U = k>>3, j = k&7)

// ---------------------------------------------------------------------------
// K1: support1 = x @ W2 -> fp8 e4m3 (x SB1) in fragment order.
// ---------------------------------------------------------------------------
__global__ __launch_bounds__(256)
void k1_xw2(const float* __restrict__ x, const float* __restrict__ W2,
            unsigned char* __restrict__ B1) {
  __shared__ __align__(16) float xs[64 * 128];
  const int t = threadIdx.x;
  const long rowbase = (long)blockIdx.x * 64;
  const f32x4* xg = (const f32x4*)(x + rowbase * 128);
  f32x4* xl = (f32x4*)xs;
#pragma unroll
  for (int i = 0; i < 8; ++i) xl[t + 256 * i] = xg[t + 256 * i];
  __syncthreads();
  const int r0 = (t >> 5) * 8;   // 8 rows per thread (8-aligned)
  const int c0 = (t & 31) * 4;   // 4 cols per thread
  float acc[8][4] = {};
  for (int k = 0; k < 128; k += 4) {
    f32x4 w[4];
#pragma unroll
    for (int kk = 0; kk < 4; ++kk) w[kk] = *(const f32x4*)(W2 + (k + kk) * 128 + c0);
#pragma unroll
    for (int i = 0; i < 8; ++i) {
      f32x4 xv = *(const f32x4*)(xs + (r0 + i) * 128 + k);
#pragma unroll
      for (int kk = 0; kk < 4; ++kk)
#pragma unroll
        for (int j = 0; j < 4; ++j) acc[i][j] += xv[kk] * w[kk][j];
    }
  }
  const long U = (rowbase + r0) >> 3;
  i32x4 wv0, wv1;
#pragma unroll
  for (int j = 0; j < 4; ++j) {
    int lo = __builtin_amdgcn_cvt_pk_fp8_f32(acc[0][j] * SB1, acc[1][j] * SB1, 0, false);
    lo     = __builtin_amdgcn_cvt_pk_fp8_f32(acc[2][j] * SB1, acc[3][j] * SB1, lo, true);
    int hi = __builtin_amdgcn_cvt_pk_fp8_f32(acc[4][j] * SB1, acc[5][j] * SB1, 0, false);
    hi     = __builtin_amdgcn_cvt_pk_fp8_f32(acc[6][j] * SB1, acc[7][j] * SB1, hi, true);
    if (j < 2) { wv0[2 * j] = lo; wv0[2 * j + 1] = hi; }
    else       { wv1[2 * (j - 2)] = lo; wv1[2 * (j - 2) + 1] = hi; }
  }
  *(i32x4*)(B1 + (U * 128 + c0) * 8)      = wv0;
  *(i32x4*)(B1 + (U * 128 + c0) * 8 + 16) = wv1;
}

// ---------------------------------------------------------------------------
// Big kernel v12 = R11 champion + pass2 package.
// 512 threads / 8 waves; 128-row tile; grid 512 = 2 blocks/CU.
// A staged through LDS via gather-source global_load_lds (4 rows x 256B per
// instruction), XOR-swizzled on both sides (rule #21).
// AMODE 0: A f32 via LDS -> cvt fp8 once; feeds MFMA + A8 side-copy.
//          A8 stores PLAIN (not NT): write-back buffering + L3 residue.
// AMODE 1: A from fp8 copy; depth-2 shift-queue register prefetch;
//          REVERSED block mapping (bid' = grid-1-bid) -> reads A8 LIFO
//          w.r.t. pass1's write order -> L3 tail hits.
// AMODE 2: AMODE 0 without the side-copy (ws fallback).
// Sync/step: stage(t+1) issued FIRST (sched_barrier-pinned), one raw
// s_barrier with exact counted vmcnt (stores/prefetch stay in flight).
// ---------------------------------------------------------------------------
template <int AMODE>
__global__ __launch_bounds__(512, 4)
void big_mm(const float* __restrict__ A, const unsigned char* __restrict__ A8r,
            unsigned char* __restrict__ A8w, const unsigned char* __restrict__ B8,
            float sc, float* __restrict__ P) {
  // LDS: B bank0 [0,8K) B bank1 [8K,16K); A bank0 [16K,48K) A bank1 [48K,80K)
  constexpr int LDSSZ = (AMODE == 1) ? 16384 : 81920;
  __shared__ __align__(16) unsigned char LB[LDSSZ];
  const int tid  = threadIdx.x;
  const int wid  = tid >> 6;     // 0..7
  const int lane = tid & 63;
  const int g    = lane >> 4;    // k-group
  const int cl   = lane & 15;    // A-row / B-col / C-col within tile
  int bid = blockIdx.x;
  if constexpr (AMODE == 1) bid = (int)gridDim.x - 1 - bid;   // LIFO vs pass1
  const int tile_m = bid & 127;
  const int s      = bid >> 7;
  const long k0 = (long)s * KSLICE;

  const char* bsrc = (const char*)B8 + k0 * 128 + (long)tid * 16;
  const long c8base = (long)bid * (64L * 8192) + (long)tid * 16;

  // A gather-stage sources: instruction q covers rows wid*16+q*4+[0,4)
  const char* asrc[4];
  int aoff[4];                   // ds_read offsets (swizzled), j=0..3
  if constexpr (AMODE != 1) {
    const int rl = lane >> 4;    // 0..3
#pragma unroll
    for (int q = 0; q < 4; ++q) {
      const int row_local = wid * 16 + q * 4 + rl;
      const int piece = ((lane & 15) * 16) ^ ((row_local & 7) << 4);
      asrc[q] = (const char*)A + ((long)(tile_m * 128 + row_local) * MN + k0) * 4 + piece;
    }
    const int row = wid * 16 + cl;
#pragma unroll
    for (int j = 0; j < 4; ++j)
      aoff[j] = 16384 + row * 256 + ((g * 64 + j * 16) ^ ((cl & 7) << 4));
  }

  f32x4 acc[8] = {};

  // prologue: stage step 0 into bank 0; AMODE1: prefetch A8(0),A8(1); drain
  if constexpr (AMODE != 1) {
#pragma unroll
    for (int q = 0; q < 4; ++q)
      async16(LB + 16384 + (wid * 4 + q) * 1024, asrc[q]);
  }
  async16(LB + wid * 1024, bsrc);
  i32x4 q8a, q8b;
  if constexpr (AMODE == 1) {
    q8a = *(const i32x4*)(A8r + c8base);
    q8b = *(const i32x4*)(A8r + c8base + 8192);
  }
  __syncthreads();

  for (int t = 0; t < NSTEPS; ++t) {
    const int bank = t & 1;
    // (1) stage (t+1) FIRST into the other bank
    if (t + 1 < NSTEPS) {
      const int nb = bank ^ 1;
      if constexpr (AMODE != 1) {
#pragma unroll
        for (int q = 0; q < 4; ++q)
          async16(LB + 16384 + nb * 32768 + (wid * 4 + q) * 1024,
                  asrc[q] + (long)(t + 1) * 256);
      }
      async16(LB + nb * 8192 + wid * 1024, bsrc + (long)(t + 1) * 8192);
    }
    __builtin_amdgcn_sched_barrier(0);   // pin stages oldest in VMEM order

    // (2) A fragment -> fp8 pk dwords
    int pk0, pk1, pk2, pk3;
    if constexpr (AMODE == 1) {
      i32x4 q8 = q8a;            // depth-2 shift queue (static indexing)
      q8a = q8b;
      if (t + 2 < NSTEPS)
        q8b = *(const i32x4*)(A8r + c8base + (long)(t + 2) * 8192);
      pk0 = q8[0]; pk1 = q8[1]; pk2 = q8[2]; pk3 = q8[3];
    } else {
      f32x4 ar0 = *(const f32x4*)(LB + bank * 32768 + aoff[0]);
      f32x4 ar1 = *(const f32x4*)(LB + bank * 32768 + aoff[1]);
      f32x4 ar2 = *(const f32x4*)(LB + bank * 32768 + aoff[2]);
      f32x4 ar3 = *(const f32x4*)(LB + bank * 32768 + aoff[3]);
      pk0 = __builtin_amdgcn_cvt_pk_fp8_f32(ar0[0] * A8S, ar0[1] * A8S, 0, false);
      pk0 = __builtin_amdgcn_cvt_pk_fp8_f32(ar0[2] * A8S, ar0[3] * A8S, pk0, true);
      pk1 = __builtin_amdgcn_cvt_pk_fp8_f32(ar1[0] * A8S, ar1[1] * A8S, 0, false);
      pk1 = __builtin_amdgcn_cvt_pk_fp8_f32(ar1[2] * A8S, ar1[3] * A8S, pk1, true);
      pk2 = __builtin_amdgcn_cvt_pk_fp8_f32(ar2[0] * A8S, ar2[1] * A8S, 0, false);
      pk2 = __builtin_amdgcn_cvt_pk_fp8_f32(ar2[2] * A8S, ar2[3] * A8S, pk2, true);
      pk3 = __builtin_amdgcn_cvt_pk_fp8_f32(ar3[0] * A8S, ar3[1] * A8S, 0, false);
      pk3 = __builtin_amdgcn_cvt_pk_fp8_f32(ar3[2] * A8S, ar3[3] * A8S, pk3, true);
      if constexpr (AMODE == 0) {
        i32x4 st = {pk0, pk1, pk2, pk3};
        *(i32x4*)(A8w + c8base + (long)t * 8192) = st;   // plain: L2/L3 buffer
      }
    }
    const long alo = ((long)(unsigned)pk1 << 32) | (unsigned)pk0;
    const long ahi = ((long)(unsigned)pk3 << 32) | (unsigned)pk2;

    // (3) MFMA: 8 col-tiles x 2 k-units (units 2g, 2g+1 of this step)
    const char* bb = (const char*)LB + bank * 8192 + g * 2048 + cl * 8;
#pragma unroll
    for (int c = 0; c < 8; ++c) {
      long b0 = *(const long*)(bb + c * 128);
      long b1 = *(const long*)(bb + 1024 + c * 128);
      acc[c] = __builtin_amdgcn_mfma_f32_16x16x32_fp8_fp8(alo, b0, acc[c], 0, 0, 0);
      acc[c] = __builtin_amdgcn_mfma_f32_16x16x32_fp8_fp8(ahi, b1, acc[c], 0, 0, 0);
    }

    // (4) retire stage(t+1) exactly; keep A8 store / A8 prefetch in flight
    if (t + 1 < NSTEPS) {
      if constexpr (AMODE == 0)      asm volatile("s_waitcnt vmcnt(1)" ::: "memory");
      else if constexpr (AMODE == 2) asm volatile("s_waitcnt vmcnt(0)" ::: "memory");
      else                           asm volatile("s_waitcnt vmcnt(1)" ::: "memory");
      __builtin_amdgcn_s_barrier();
    }
  }

  // C/D layout (HW-verified, dtype-independent): col=lane&15, row=4*(lane>>4)+q
  float* pb = P + ((long)s * MN + tile_m * 128 + wid * 16) * 128;
#pragma unroll
  for (int c = 0; c < 8; ++c)
#pragma unroll
    for (int q = 0; q < 4; ++q)
      __builtin_nontemporal_store(acc[c][q] * sc,
                                  &pb[(g * 4 + q) * 128 + 16 * c + cl]);
}

// ---------------------------------------------------------------------------
// K3: LH = sum_s P[s] + b2 (tile in LDS); then
//     B2 = fp8frag(LH @ W4 * SB2);  R = LH @ res_w^T + res_b + b4
// ---------------------------------------------------------------------------
__global__ __launch_bounds__(256)
void k3_mid(const float* __restrict__ P, const float* __restrict__ b2,
            const float* __restrict__ W4, const float* __restrict__ res_w,
            const float* __restrict__ b4, const float* __restrict__ res_b,
            unsigned char* __restrict__ B2, float* __restrict__ Rr) {
  __shared__ __align__(16) float hs[64 * 128];
  const int t = threadIdx.x;
  const long rowbase = (long)blockIdx.x * 64;
  const long base = rowbase * 32;            // f32x4 units (128/4 per row)
  const f32x4* P0 = (const f32x4*)P + base;
  const f32x4* P1 = (const f32x4*)P + (long)MN * 32 + base;
  const f32x4* P2 = (const f32x4*)P + 2L * MN * 32 + base;
  const f32x4* P3 = (const f32x4*)P + 3L * MN * 32 + base;
  const f32x4* b2v = (const f32x4*)b2;
  f32x4* hl = (f32x4*)hs;
#pragma unroll
  for (int i = 0; i < 8; ++i) {
    int idx = t + 256 * i;
    f32x4 v = __builtin_nontemporal_load(P0 + idx);
    v += __builtin_nontemporal_load(P1 + idx);
    v += __builtin_nontemporal_load(P2 + idx);
    v += __builtin_nontemporal_load(P3 + idx);
    hl[idx] = v + b2v[idx & 31];
  }
  __syncthreads();
  const int r0 = (t >> 5) * 8;
  const int c0 = (t & 31) * 4;
  float acc2[8][4] = {};
  float accR[8][4] = {};
  for (int k = 0; k < 128; k += 4) {
    f32x4 w4v[4], rwv[4];
#pragma unroll
    for (int kk = 0; kk < 4; ++kk) w4v[kk] = *(const f32x4*)(W4 + (k + kk) * 128 + c0);
#pragma unroll
    for (int j = 0; j < 4; ++j) rwv[j] = *(const f32x4*)(res_w + (c0 + j) * 128 + k);
#pragma unroll
    for (int i = 0; i < 8; ++i) {
      f32x4 xv = *(const f32x4*)(hs + (r0 + i) * 128 + k);
#pragma unroll
      for (int kk = 0; kk < 4; ++kk)
#pragma unroll
        for (int j = 0; j < 4; ++j) {
          acc2[i][j] += xv[kk] * w4v[kk][j];
          accR[i][j] += xv[kk] * rwv[j][kk];
        }
    }
  }
  const long U = (rowbase + r0) >> 3;
  i32x4 wv0, wv1;
#pragma unroll
  for (int j = 0; j < 4; ++j) {
    int lo = __builtin_amdgcn_cvt_pk_fp8_f32(acc2[0][j] * SB2, acc2[1][j] * SB2, 0, false);
    lo     = __builtin_amdgcn_cvt_pk_fp8_f32(acc2[2][j] * SB2, acc2[3][j] * SB2, lo, true);
    int hi = __builtin_amdgcn_cvt_pk_fp8_f32(acc2[4][j] * SB2, acc2[5][j] * SB2, 0, false);
    hi     = __builtin_amdgcn_cvt_pk_fp8_f32(acc2[6][j] * SB2, acc2[7][j] * SB2, hi, true);
    if (j < 2) { wv0[2 * j] = lo; wv0[2 * j + 1] = hi; }
    else       { wv1[2 * (j - 2)] = lo; wv1[2 * (j - 2) + 1] = hi; }
  }
  *(i32x4*)(B2 + (U * 128 + c0) * 8)      = wv0;
  *(i32x4*)(B2 + (U * 128 + c0) * 8 + 16) = wv1;

  const f32x4 b4v = *(const f32x4*)(b4 + c0);
  const f32x4 rbv = *(const f32x4*)(res_b + c0);
#pragma unroll
  for (int i = 0; i < 8; ++i) {
    f32x4 rv;
#pragma unroll
    for (int j = 0; j < 4; ++j) rv[j] = accR[i][j];
    rv += b4v + rbv;
    *(f32x4*)(Rr + (rowbase + r0 + i) * 128 + c0) = rv;
  }
}

// ---------------------------------------------------------------------------
// K5: out = sum_s P[s] + R
// ---------------------------------------------------------------------------
__global__ __launch_bounds__(256)
void k5_out(const float* __restrict__ P, const float* __restrict__ Rr,
            float* __restrict__ out) {
  const long i = (long)blockIdx.x * 256 + threadIdx.x;   // f32x4 index
  const f32x4* P0 = (const f32x4*)P;
  const f32x4* P1 = P0 + (long)MN * 32;
  const f32x4* P2 = P0 + 2L * MN * 32;
  const f32x4* P3 = P0 + 3L * MN * 32;
  f32x4 v = __builtin_nontemporal_load(P0 + i);
  v += __builtin_nontemporal_load(P1 + i);
  v += __builtin_nontemporal_load(P2 + i);
  v += __builtin_nontemporal_load(P3 + i);
  v += *((const f32x4*)Rr + i);
  __builtin_nontemporal_store(v, (f32x4*)out + i);
}

extern "C" void kernel_launch(void* const* d_in, const int* in_sizes, int n_in,
                              void* d_out, int out_size, void* d_ws, size_t ws_size,
                              hipStream_t stream) {
  const float* x     = (const float*)d_in[0];
  const float* adj   = (const float*)d_in[1];
  const float* W2    = (const float*)d_in[2];
  const float* b2    = (const float*)d_in[3];
  const float* W4    = (const float*)d_in[4];
  const float* b4    = (const float*)d_in[5];
  const float* res_w = (const float*)d_in[6];
  const float* res_b = (const float*)d_in[7];
  float* out = (float*)d_out;

  char* ws = (char*)d_ws;
  unsigned char* B1 = (unsigned char*)ws;                  // 2 MB fp8-frag s1
  unsigned char* B2 = (unsigned char*)(ws + (4L << 20));   // 2 MB fp8-frag s2
  float* Rr = (float*)(ws + (8L << 20));                   // 8 MB residual
  float* P  = (float*)(ws + (16L << 20));                  // 32 MB f32 partials
  unsigned char* A8 = (unsigned char*)(ws + (48L << 20));  // 256 MB fp8 adj

  const size_t need = (48L << 20) + (size_t)MN * MN;  // 316.8 MB
  const bool fp8_copy = ws_size >= need;

  k1_xw2<<<dim3(256), dim3(256), 0, stream>>>(x, W2, B1);
  if (fp8_copy) {
    big_mm<0><<<dim3(128 * SPLITS), dim3(512), 0, stream>>>(adj, nullptr, A8, B1, SC1, P);
    k3_mid<<<dim3(256), dim3(256), 0, stream>>>(P, b2, W4, res_w, b4, res_b, B2, Rr);
    big_mm<1><<<dim3(128 * SPLITS), dim3(512), 0, stream>>>(nullptr, A8, nullptr, B2, SC2, P);
  } else {
    big_mm<2><<<dim3(128 * SPLITS), dim3(512), 0, stream>>>(adj, nullptr, nullptr, B1, SC1, P);
    k3_mid<<<dim3(256), dim3(256), 0, stream>>>(P, b2, W4, res_w, b4, res_b, B2, Rr);
    big_mm<2><<<dim3(128 * SPLITS), dim3(512), 0, stream>>>(adj, nullptr, nullptr, B2, SC2, P);
  }
  k5_out<<<dim3(2048), dim3(256), 0, stream>>>(P, Rr, out);
}

// Round 14
// 420.136 us; speedup vs baseline: 1.2357x; 1.0143x over previous
//
#include <hip/hip_runtime.h>
#include <hip/hip_bf16.h>

#define MN 16384
#define SPLITS 4
#define KSLICE (MN / SPLITS)     // 4096
#define BK 64
#define NSTEPS (KSLICE / BK)     // 64

typedef float f32x4 __attribute__((ext_vector_type(4)));
typedef int   i32x4 __attribute__((ext_vector_type(4)));
typedef unsigned short u16x8 __attribute__((ext_vector_type(8)));

#define A8S 32768.0f             // adj * 2^15 in [0,2)
#define SB1 64.0f                // support1 * 2^6
#define SB2 4096.0f              // support2 * 2^12
#define SC1 (1.0f / (32768.0f * 64.0f))     // 2^-21
#define SC2 (1.0f / (32768.0f * 4096.0f))   // 2^-27

__device__ __forceinline__ unsigned short f2bf(float f) {
  unsigned u = __builtin_bit_cast(unsigned, f);
  u += 0x7FFFu + ((u >> 16) & 1u);   // round-to-nearest-even
  return (unsigned short)(u >> 16);
}
__device__ __forceinline__ float bf2f(unsigned short h) {
  unsigned u = ((unsigned)h) << 16;
  return __builtin_bit_cast(float, u);
}

__device__ __forceinline__ void async16(void* lds, const void* g) {
  __builtin_amdgcn_global_load_lds(
      (const __attribute__((address_space(1))) unsigned int*)g,
      (__attribute__((address_space(3))) unsigned int*)lds, 16, 0, 0);
}

// fp8-fragment order for a [K x 128] operand: byte[(U*128 + col)*8 + j]
// holds fp8(val[k = U*8 + j][col]).  (unit U = k>>3, j = k&7)

// ---------------------------------------------------------------------------
// K1: support1 = x @ W2 -> fp8 e4m3 (x SB1) in fragment order.
// ---------------------------------------------------------------------------
__global__ __launch_bounds__(256)
void k1_xw2(const float* __restrict__ x, const float* __restrict__ W2,
            unsigned char* __restrict__ B1) {
  __shared__ __align__(16) float xs[64 * 128];
  const int t = threadIdx.x;
  const long rowbase = (long)blockIdx.x * 64;
  const f32x4* xg = (const f32x4*)(x + rowbase * 128);
  f32x4* xl = (f32x4*)xs;
#pragma unroll
  for (int i = 0; i < 8; ++i) xl[t + 256 * i] = xg[t + 256 * i];
  __syncthreads();
  const int r0 = (t >> 5) * 8;   // 8 rows per thread (8-aligned)
  const int c0 = (t & 31) * 4;   // 4 cols per thread
  float acc[8][4] = {};
  for (int k = 0; k < 128; k += 4) {
    f32x4 w[4];
#pragma unroll
    for (int kk = 0; kk < 4; ++kk) w[kk] = *(const f32x4*)(W2 + (k + kk) * 128 + c0);
#pragma unroll
    for (int i = 0; i < 8; ++i) {
      f32x4 xv = *(const f32x4*)(xs + (r0 + i) * 128 + k);
#pragma unroll
      for (int kk = 0; kk < 4; ++kk)
#pragma unroll
        for (int j = 0; j < 4; ++j) acc[i][j] += xv[kk] * w[kk][j];
    }
  }
  const long U = (rowbase + r0) >> 3;
  i32x4 wv0, wv1;
#pragma unroll
  for (int j = 0; j < 4; ++j) {
    int lo = __builtin_amdgcn_cvt_pk_fp8_f32(acc[0][j] * SB1, acc[1][j] * SB1, 0, false);
    lo     = __builtin_amdgcn_cvt_pk_fp8_f32(acc[2][j] * SB1, acc[3][j] * SB1, lo, true);
    int hi = __builtin_amdgcn_cvt_pk_fp8_f32(acc[4][j] * SB1, acc[5][j] * SB1, 0, false);
    hi     = __builtin_amdgcn_cvt_pk_fp8_f32(acc[6][j] * SB1, acc[7][j] * SB1, hi, true);
    if (j < 2) { wv0[2 * j] = lo; wv0[2 * j + 1] = hi; }
    else       { wv1[2 * (j - 2)] = lo; wv1[2 * (j - 2) + 1] = hi; }
  }
  *(i32x4*)(B1 + (U * 128 + c0) * 8)      = wv0;
  *(i32x4*)(B1 + (U * 128 + c0) * 8 + 16) = wv1;
}

// ---------------------------------------------------------------------------
// Big kernel v13 = R11 champion with bf16 split-K partials.
// 512 threads / 8 waves; 128-row tile; grid 512 = 2 blocks/CU.
// A staged through LDS via gather-source global_load_lds (4 rows x 256B per
// instruction), XOR-swizzled on both sides (rule #21).
// AMODE 0: A f32 via LDS -> cvt fp8 once; feeds MFMA + A8 side-copy (NT).
// AMODE 1: A from fp8 copy (1 dwordx4/lane/step, reg prefetch 1 step).
// AMODE 2: AMODE 0 without the side-copy (ws fallback).
// Sync/step: stage(t+1) issued FIRST (sched_barrier-pinned), one raw
// s_barrier with exact counted vmcnt (stores/prefetch stay in flight).
// Epilogue: P stored as bf16 (halves partial traffic; error ~0.4% of
// partials that already carry 3% fp8 operand noise).
// ---------------------------------------------------------------------------
template <int AMODE>
__global__ __launch_bounds__(512, 4)
void big_mm(const float* __restrict__ A, const unsigned char* __restrict__ A8r,
            unsigned char* __restrict__ A8w, const unsigned char* __restrict__ B8,
            float sc, unsigned short* __restrict__ Pb) {
  // LDS: B bank0 [0,8K) B bank1 [8K,16K); A bank0 [16K,48K) A bank1 [48K,80K)
  constexpr int LDSSZ = (AMODE == 1) ? 16384 : 81920;
  __shared__ __align__(16) unsigned char LB[LDSSZ];
  const int tid  = threadIdx.x;
  const int wid  = tid >> 6;     // 0..7
  const int lane = tid & 63;
  const int g    = lane >> 4;    // k-group
  const int cl   = lane & 15;    // A-row / B-col / C-col within tile
  const int tile_m = blockIdx.x & 127;
  const int s      = blockIdx.x >> 7;
  const long k0 = (long)s * KSLICE;

  const char* bsrc = (const char*)B8 + k0 * 128 + (long)tid * 16;
  const long c8base = (long)blockIdx.x * (64L * 8192) + (long)tid * 16;

  // A gather-stage sources: instruction q covers rows wid*16+q*4+[0,4)
  const char* asrc[4];
  int aoff[4];                   // ds_read offsets (swizzled), j=0..3
  if constexpr (AMODE != 1) {
    const int rl = lane >> 4;    // 0..3
#pragma unroll
    for (int q = 0; q < 4; ++q) {
      const int row_local = wid * 16 + q * 4 + rl;
      const int piece = ((lane & 15) * 16) ^ ((row_local & 7) << 4);
      asrc[q] = (const char*)A + ((long)(tile_m * 128 + row_local) * MN + k0) * 4 + piece;
    }
    const int row = wid * 16 + cl;
#pragma unroll
    for (int j = 0; j < 4; ++j)
      aoff[j] = 16384 + row * 256 + ((g * 64 + j * 16) ^ ((cl & 7) << 4));
  }

  f32x4 acc[8] = {};

  // prologue: stage step 0 into bank 0; AMODE1: prefetch A8(0); full drain
  if constexpr (AMODE != 1) {
#pragma unroll
    for (int q = 0; q < 4; ++q)
      async16(LB + 16384 + (wid * 4 + q) * 1024, asrc[q]);
  }
  async16(LB + wid * 1024, bsrc);
  i32x4 q8n;
  if constexpr (AMODE == 1) q8n = *(const i32x4*)(A8r + c8base);
  __syncthreads();

  for (int t = 0; t < NSTEPS; ++t) {
    const int bank = t & 1;
    // (1) stage (t+1) FIRST into the other bank
    if (t + 1 < NSTEPS) {
      const int nb = bank ^ 1;
      if constexpr (AMODE != 1) {
#pragma unroll
        for (int q = 0; q < 4; ++q)
          async16(LB + 16384 + nb * 32768 + (wid * 4 + q) * 1024,
                  asrc[q] + (long)(t + 1) * 256);
      }
      async16(LB + nb * 8192 + wid * 1024, bsrc + (long)(t + 1) * 8192);
    }
    __builtin_amdgcn_sched_barrier(0);   // pin stages oldest in VMEM order

    // (2) A fragment -> fp8 pk dwords
    int pk0, pk1, pk2, pk3;
    if constexpr (AMODE == 1) {
      i32x4 q8 = q8n;
      if (t + 1 < NSTEPS)
        q8n = *(const i32x4*)(A8r + c8base + (long)(t + 1) * 8192);
      pk0 = q8[0]; pk1 = q8[1]; pk2 = q8[2]; pk3 = q8[3];
    } else {
      f32x4 ar0 = *(const f32x4*)(LB + bank * 32768 + aoff[0]);
      f32x4 ar1 = *(const f32x4*)(LB + bank * 32768 + aoff[1]);
      f32x4 ar2 = *(const f32x4*)(LB + bank * 32768 + aoff[2]);
      f32x4 ar3 = *(const f32x4*)(LB + bank * 32768 + aoff[3]);
      pk0 = __builtin_amdgcn_cvt_pk_fp8_f32(ar0[0] * A8S, ar0[1] * A8S, 0, false);
      pk0 = __builtin_amdgcn_cvt_pk_fp8_f32(ar0[2] * A8S, ar0[3] * A8S, pk0, true);
      pk1 = __builtin_amdgcn_cvt_pk_fp8_f32(ar1[0] * A8S, ar1[1] * A8S, 0, false);
      pk1 = __builtin_amdgcn_cvt_pk_fp8_f32(ar1[2] * A8S, ar1[3] * A8S, pk1, true);
      pk2 = __builtin_amdgcn_cvt_pk_fp8_f32(ar2[0] * A8S, ar2[1] * A8S, 0, false);
      pk2 = __builtin_amdgcn_cvt_pk_fp8_f32(ar2[2] * A8S, ar2[3] * A8S, pk2, true);
      pk3 = __builtin_amdgcn_cvt_pk_fp8_f32(ar3[0] * A8S, ar3[1] * A8S, 0, false);
      pk3 = __builtin_amdgcn_cvt_pk_fp8_f32(ar3[2] * A8S, ar3[3] * A8S, pk3, true);
      if constexpr (AMODE == 0) {
        i32x4 st = {pk0, pk1, pk2, pk3};
        __builtin_nontemporal_store(st, (i32x4*)(A8w + c8base + (long)t * 8192));
      }
    }
    const long alo = ((long)(unsigned)pk1 << 32) | (unsigned)pk0;
    const long ahi = ((long)(unsigned)pk3 << 32) | (unsigned)pk2;

    // (3) MFMA: 8 col-tiles x 2 k-units (units 2g, 2g+1 of this step)
    const char* bb = (const char*)LB + bank * 8192 + g * 2048 + cl * 8;
#pragma unroll
    for (int c = 0; c < 8; ++c) {
      long b0 = *(const long*)(bb + c * 128);
      long b1 = *(const long*)(bb + 1024 + c * 128);
      acc[c] = __builtin_amdgcn_mfma_f32_16x16x32_fp8_fp8(alo, b0, acc[c], 0, 0, 0);
      acc[c] = __builtin_amdgcn_mfma_f32_16x16x32_fp8_fp8(ahi, b1, acc[c], 0, 0, 0);
    }

    // (4) retire stage(t+1) exactly; keep A8 store / A8 prefetch in flight
    if (t + 1 < NSTEPS) {
      if constexpr (AMODE == 0)      asm volatile("s_waitcnt vmcnt(1)" ::: "memory");
      else if constexpr (AMODE == 2) asm volatile("s_waitcnt vmcnt(0)" ::: "memory");
      else                           asm volatile("s_waitcnt vmcnt(1)" ::: "memory");
      __builtin_amdgcn_s_barrier();
    }
  }

  // C/D layout (HW-verified, dtype-independent): col=lane&15, row=4*(lane>>4)+q
  unsigned short* pb = Pb + ((long)s * MN + tile_m * 128 + wid * 16) * 128;
#pragma unroll
  for (int c = 0; c < 8; ++c)
#pragma unroll
    for (int q = 0; q < 4; ++q)
      __builtin_nontemporal_store(f2bf(acc[c][q] * sc),
                                  &pb[(g * 4 + q) * 128 + 16 * c + cl]);
}

// ---------------------------------------------------------------------------
// K3: LH = sum_s bf16(P[s]) + b2 (tile in LDS); then
//     B2 = fp8frag(LH @ W4 * SB2);  R = LH @ res_w^T + res_b + b4
// ---------------------------------------------------------------------------
__global__ __launch_bounds__(256)
void k3_mid(const unsigned short* __restrict__ Pb, const float* __restrict__ b2,
            const float* __restrict__ W4, const float* __restrict__ res_w,
            const float* __restrict__ b4, const float* __restrict__ res_b,
            unsigned char* __restrict__ B2, float* __restrict__ Rr) {
  __shared__ __align__(16) float hs[64 * 128];
  const int t = threadIdx.x;
  const long rowbase = (long)blockIdx.x * 64;
  const u16x8* Pu = (const u16x8*)(Pb + rowbase * 128);   // units of 8 elems
  const long SLU = (long)MN * 16;                          // u16x8 units/slice
#pragma unroll
  for (int i = 0; i < 4; ++i) {
    const int u = t + 256 * i;         // 1024 units = 8192 elems
    u16x8 q0 = __builtin_nontemporal_load(Pu + u);
    u16x8 q1 = __builtin_nontemporal_load(Pu + SLU + u);
    u16x8 q2 = __builtin_nontemporal_load(Pu + 2 * SLU + u);
    u16x8 q3 = __builtin_nontemporal_load(Pu + 3 * SLU + u);
#pragma unroll
    for (int j = 0; j < 8; ++j) {
      const int col = (u * 8 + j) & 127;
      hs[u * 8 + j] = bf2f(q0[j]) + bf2f(q1[j]) + bf2f(q2[j]) + bf2f(q3[j]) + b2[col];
    }
  }
  __syncthreads();
  const int r0 = (t >> 5) * 8;
  const int c0 = (t & 31) * 4;
  float acc2[8][4] = {};
  float accR[8][4] = {};
  for (int k = 0; k < 128; k += 4) {
    f32x4 w4v[4], rwv[4];
#pragma unroll
    for (int kk = 0; kk < 4; ++kk) w4v[kk] = *(const f32x4*)(W4 + (k + kk) * 128 + c0);
#pragma unroll
    for (int j = 0; j < 4; ++j) rwv[j] = *(const f32x4*)(res_w + (c0 + j) * 128 + k);
#pragma unroll
    for (int i = 0; i < 8; ++i) {
      f32x4 xv = *(const f32x4*)(hs + (r0 + i) * 128 + k);
#pragma unroll
      for (int kk = 0; kk < 4; ++kk)
#pragma unroll
        for (int j = 0; j < 4; ++j) {
          acc2[i][j] += xv[kk] * w4v[kk][j];
          accR[i][j] += xv[kk] * rwv[j][kk];
        }
    }
  }
  const long U = (rowbase + r0) >> 3;
  i32x4 wv0, wv1;
#pragma unroll
  for (int j = 0; j < 4; ++j) {
    int lo = __builtin_amdgcn_cvt_pk_fp8_f32(acc2[0][j] * SB2, acc2[1][j] * SB2, 0, false);
    lo     = __builtin_amdgcn_cvt_pk_fp8_f32(acc2[2][j] * SB2, acc2[3][j] * SB2, lo, true);
    int hi = __builtin_amdgcn_cvt_pk_fp8_f32(acc2[4][j] * SB2, acc2[5][j] * SB2, 0, false);
    hi     = __builtin_amdgcn_cvt_pk_fp8_f32(acc2[6][j] * SB2, acc2[7][j] * SB2, hi, true);
    if (j < 2) { wv0[2 * j] = lo; wv0[2 * j + 1] = hi; }
    else       { wv1[2 * (j - 2)] = lo; wv1[2 * (j - 2) + 1] = hi; }
  }
  *(i32x4*)(B2 + (U * 128 + c0) * 8)      = wv0;
  *(i32x4*)(B2 + (U * 128 + c0) * 8 + 16) = wv1;

  const f32x4 b4v = *(const f32x4*)(b4 + c0);
  const f32x4 rbv = *(const f32x4*)(res_b + c0);
#pragma unroll
  for (int i = 0; i < 8; ++i) {
    f32x4 rv;
#pragma unroll
    for (int j = 0; j < 4; ++j) rv[j] = accR[i][j];
    rv += b4v + rbv;
    *(f32x4*)(Rr + (rowbase + r0 + i) * 128 + c0) = rv;
  }
}

// ---------------------------------------------------------------------------
// K5: out = sum_s bf16(P[s]) + R    (8 elems / thread)
// ---------------------------------------------------------------------------
__global__ __launch_bounds__(256)
void k5_out(const unsigned short* __restrict__ Pb, const float* __restrict__ Rr,
            float* __restrict__ out) {
  const long u = (long)blockIdx.x * 256 + threadIdx.x;   // u16x8 unit
  const u16x8* Pu = (const u16x8*)Pb;
  const long SLU = (long)MN * 16;
  u16x8 q0 = __builtin_nontemporal_load(Pu + u);
  u16x8 q1 = __builtin_nontemporal_load(Pu + SLU + u);
  u16x8 q2 = __builtin_nontemporal_load(Pu + 2 * SLU + u);
  u16x8 q3 = __builtin_nontemporal_load(Pu + 3 * SLU + u);
  f32x4 r0 = *((const f32x4*)Rr + 2 * u);
  f32x4 r1 = *((const f32x4*)Rr + 2 * u + 1);
  f32x4 v0, v1;
#pragma unroll
  for (int j = 0; j < 4; ++j) {
    v0[j] = bf2f(q0[j]) + bf2f(q1[j]) + bf2f(q2[j]) + bf2f(q3[j]) + r0[j];
    v1[j] = bf2f(q0[4 + j]) + bf2f(q1[4 + j]) + bf2f(q2[4 + j]) + bf2f(q3[4 + j]) + r1[j];
  }
  __builtin_nontemporal_store(v0, (f32x4*)out + 2 * u);
  __builtin_nontemporal_store(v1, (f32x4*)out + 2 * u + 1);
}

extern "C" void kernel_launch(void* const* d_in, const int* in_sizes, int n_in,
                              void* d_out, int out_size, void* d_ws, size_t ws_size,
                              hipStream_t stream) {
  const float* x     = (const float*)d_in[0];
  const float* adj   = (const float*)d_in[1];
  const float* W2    = (const float*)d_in[2];
  const float* b2    = (const float*)d_in[3];
  const float* W4    = (const float*)d_in[4];
  const float* b4    = (const float*)d_in[5];
  const float* res_w = (const float*)d_in[6];
  const float* res_b = (const float*)d_in[7];
  float* out = (float*)d_out;

  char* ws = (char*)d_ws;
  unsigned char* B1 = (unsigned char*)ws;                  // 2 MB fp8-frag s1
  unsigned char* B2 = (unsigned char*)(ws + (4L << 20));   // 2 MB fp8-frag s2
  float* Rr = (float*)(ws + (8L << 20));                   // 8 MB residual
  unsigned short* Pb = (unsigned short*)(ws + (16L << 20)); // 16 MB bf16 partials
  unsigned char* A8 = (unsigned char*)(ws + (48L << 20));  // 256 MB fp8 adj

  const size_t need = (48L << 20) + (size_t)MN * MN;  // 316.8 MB
  const bool fp8_copy = ws_size >= need;

  k1_xw2<<<dim3(256), dim3(256), 0, stream>>>(x, W2, B1);
  if (fp8_copy) {
    big_mm<0><<<dim3(128 * SPLITS), dim3(512), 0, stream>>>(adj, nullptr, A8, B1, SC1, Pb);
    k3_mid<<<dim3(256), dim3(256), 0, stream>>>(Pb, b2, W4, res_w, b4, res_b, B2, Rr);
    big_mm<1><<<dim3(128 * SPLITS), dim3(512), 0, stream>>>(nullptr, A8, nullptr, B2, SC2, Pb);
  } else {
    big_mm<2><<<dim3(128 * SPLITS), dim3(512), 0, stream>>>(adj, nullptr, nullptr, B1, SC1, Pb);
    k3_mid<<<dim3(256), dim3(256), 0, stream>>>(Pb, b2, W4, res_w, b4, res_b, B2, Rr);
    big_mm<2><<<dim3(128 * SPLITS), dim3(512), 0, stream>>>(adj, nullptr, nullptr, B2, SC2, Pb);
  }
  k5_out<<<dim3(1024), dim3(256), 0, stream>>>(Pb, Rr, out);
}